// Round 7
// baseline (274.900 us; speedup 1.0000x reference)
//
#include <hip/hip_runtime.h>
#include <hip/hip_fp16.h>

#define B_SZ 4
#define CIN  256
#define CP   128
#define NN   4096
#define NT   32          // 128-row n-tiles per batch (softmax partials)
#define KSL  4           // k-slices in y_gemm (K=1024 each)

typedef _Float16 half_t;
typedef _Float16 f16x8 __attribute__((ext_vector_type(8)));
typedef float f32x4 __attribute__((ext_vector_type(4)));

#define GPTR(p) ((const __attribute__((address_space(1))) void*)(p))
#define LPTR(p) ((__attribute__((address_space(3))) void*)(p))

__device__ __forceinline__ float wave_sum64(float v){
  #pragma unroll
  for (int o = 32; o > 0; o >>= 1) v += __shfl_xor(v, o, 64);
  return v;
}

// ---------------- K0a: split W*16 into fp16 hi/lo ---------------------------
__global__ __launch_bounds__(256) void split_w(
    const float* __restrict__ Wt, const float* __restrict__ Wp,
    const float* __restrict__ Wg, half_t* __restrict__ Wh,
    half_t* __restrict__ Wl)
{
  const int sel = blockIdx.x;
  const float* W = (sel == 0) ? Wt : ((sel == 1) ? Wp : Wg);
  half_t* oh = Wh + sel * (CP * CIN);
  half_t* ol = Wl + sel * (CP * CIN);
  #pragma unroll
  for (int i = 0; i < 8; ++i){
    int i4 = blockIdx.y * 2048 + threadIdx.x + i * 256;
    float4 v = ((const float4*)W)[i4];
    v.x *= 16.f; v.y *= 16.f; v.z *= 16.f; v.w *= 16.f;
    union { half_t h[4]; uint2 u; } hh, ll;
    hh.h[0] = (half_t)v.x; ll.h[0] = (half_t)(v.x - (float)hh.h[0]);
    hh.h[1] = (half_t)v.y; ll.h[1] = (half_t)(v.y - (float)hh.h[1]);
    hh.h[2] = (half_t)v.z; ll.h[2] = (half_t)(v.z - (float)hh.h[2]);
    hh.h[3] = (half_t)v.w; ll.h[3] = (half_t)(v.w - (float)hh.h[3]);
    *(uint2*)(oh + i4 * 4) = hh.u;
    *(uint2*)(ol + i4 * 4) = ll.u;
  }
}

// ---------------- K0b: transpose-split x -> xT hi/lo [b][n][c] --------------
__global__ __launch_bounds__(256) void split_x(
    const float* __restrict__ x, half_t* __restrict__ xTh,
    half_t* __restrict__ xTl)
{
  const int b  = blockIdx.z;
  const int c0 = blockIdx.y * 64;
  const int n0 = blockIdx.x * 64;
  __shared__ float lds[64][68];
  const int tid = threadIdx.x;
  #pragma unroll
  for (int i = 0; i < 4; ++i){
    int idx = tid + i * 256;
    int cr = idx >> 4, nq = idx & 15;
    float4 v = *(const float4*)(x + ((size_t)b * CIN + c0 + cr) * NN + n0 + nq * 4);
    *(float4*)&lds[cr][nq * 4] = v;
  }
  __syncthreads();
  #pragma unroll
  for (int i = 0; i < 8; ++i){
    int idx = tid + i * 256;
    int nl = idx >> 5;
    int cp = (idx & 31) * 2;
    float v0 = lds[cp][nl], v1 = lds[cp + 1][nl];
    half_t h0 = (half_t)v0, h1 = (half_t)v1;
    half_t l0 = (half_t)(v0 - (float)h0), l1 = (half_t)(v1 - (float)h1);
    union { half_t h[2]; unsigned int u; } ph, pl;
    ph.h[0] = h0; ph.h[1] = h1;
    pl.h[0] = l0; pl.h[1] = l1;
    size_t o = ((size_t)b * NN + n0 + nl) * CIN + c0 + cp;
    *(unsigned int*)(xTh + o) = ph.u;
    *(unsigned int*)(xTl + o) = pl.u;
  }
}

// ---------------- K1: t/p/g via fp16 3-slab MFMA ----------------------------
__global__ __launch_bounds__(256) void tpg_gemm(
    const half_t* __restrict__ Wh, const half_t* __restrict__ Wl,
    const half_t* __restrict__ xTh, const half_t* __restrict__ xTl,
    half_t* __restrict__ tTh, half_t* __restrict__ tTl,
    half_t* __restrict__ pTh, half_t* __restrict__ pTl,
    half_t* __restrict__ gF)
{
  const int b   = blockIdx.z;
  const int sel = blockIdx.y;
  const int n0  = blockIdx.x * 64;
  const half_t* Ah_g = Wh + sel * (CP * CIN);
  const half_t* Al_g = Wl + sel * (CP * CIN);
  const half_t* Bh_g = xTh + ((size_t)b * NN + n0) * CIN;
  const half_t* Bl_g = xTl + ((size_t)b * NN + n0) * CIN;

  __shared__ half_t lds[24576];   // Ah 0 | Al 8192 | Bh 16384 | Bl 20480
  const int tid = threadIdx.x;
  const int wid = tid >> 6, lane = tid & 63;
  const int wo = wid >> 1, wn = wid & 1;
  const int lr = lane & 15, lq = lane >> 4;

  f32x4 acc[4][2];
  #pragma unroll
  for (int i = 0; i < 4; ++i)
    #pragma unroll
    for (int j = 0; j < 2; ++j) acc[i][j] = (f32x4){0.f,0.f,0.f,0.f};

  #pragma unroll 1
  for (int kc = 0; kc < CIN; kc += 64){
    #pragma unroll
    for (int it = 0; it < 4; ++it){
      int seg = wid * 4 + it;
      int row = seg * 8 + (lane >> 3);
      int us  = (lane & 7) ^ (row & 7);
      size_t go = (size_t)row * CIN + kc + us * 8;
      __builtin_amdgcn_global_load_lds(GPTR(Ah_g + go), LPTR(lds + seg*512), 16, 0, 0);
      __builtin_amdgcn_global_load_lds(GPTR(Al_g + go), LPTR(lds + 8192 + seg*512), 16, 0, 0);
    }
    #pragma unroll
    for (int it = 0; it < 2; ++it){
      int seg = wid * 2 + it;
      int row = seg * 8 + (lane >> 3);
      int us  = (lane & 7) ^ (row & 7);
      size_t go = (size_t)row * CIN + kc + us * 8;
      __builtin_amdgcn_global_load_lds(GPTR(Bh_g + go), LPTR(lds + 16384 + seg*512), 16, 0, 0);
      __builtin_amdgcn_global_load_lds(GPTR(Bl_g + go), LPTR(lds + 20480 + seg*512), 16, 0, 0);
    }
    asm volatile("s_waitcnt vmcnt(0)" ::: "memory");
    __syncthreads();

    #pragma unroll
    for (int kk = 0; kk < 2; ++kk){
      f16x8 ah[4], al4[4], bh[2], bl[2];
      #pragma unroll
      for (int f = 0; f < 4; ++f){
        int rA = wo * 64 + f * 16 + lr;
        int cA = (kk*32 + lq*8) ^ ((rA & 7) * 8);
        ah[f]  = *(const f16x8*)(lds + rA * 64 + cA);
        al4[f] = *(const f16x8*)(lds + 8192 + rA * 64 + cA);
      }
      #pragma unroll
      for (int f = 0; f < 2; ++f){
        int rB = wn * 32 + f * 16 + lr;
        int cB = (kk*32 + lq*8) ^ ((rB & 7) * 8);
        bh[f] = *(const f16x8*)(lds + 16384 + rB * 64 + cB);
        bl[f] = *(const f16x8*)(lds + 20480 + rB * 64 + cB);
      }
      #pragma unroll
      for (int fo = 0; fo < 4; ++fo)
        #pragma unroll
        for (int fn = 0; fn < 2; ++fn){
          acc[fo][fn] = __builtin_amdgcn_mfma_f32_16x16x32_f16(ah[fo],  bh[fn], acc[fo][fn], 0,0,0);
          acc[fo][fn] = __builtin_amdgcn_mfma_f32_16x16x32_f16(al4[fo], bh[fn], acc[fo][fn], 0,0,0);
          acc[fo][fn] = __builtin_amdgcn_mfma_f32_16x16x32_f16(ah[fo],  bl[fn], acc[fo][fn], 0,0,0);
        }
    }
    __syncthreads();
  }

  if (sel < 2){
    half_t* Ohi = ((sel == 0) ? tTh : pTh) + (size_t)b * NN * CP;
    half_t* Olo = ((sel == 0) ? tTl : pTl) + (size_t)b * NN * CP;
    float (*ldsT)[132] = (float (*)[132])lds;
    #pragma unroll
    for (int fo = 0; fo < 4; ++fo)
      #pragma unroll
      for (int fn = 0; fn < 2; ++fn)
        #pragma unroll
        for (int r = 0; r < 4; ++r){
          int n = wn * 32 + fn * 16 + lr;
          int o = wo * 64 + fo * 16 + lq * 4 + r;
          ldsT[n][o] = acc[fo][fn][r] * 0.0625f;
        }
    __syncthreads();
    #pragma unroll
    for (int it = 0; it < 16; ++it){
      int idx = tid + it * 256;
      int nl = idx >> 6;
      int cp = (idx & 63) * 2;
      float v0 = ldsT[nl][cp], v1 = ldsT[nl][cp + 1];
      half_t h0 = (half_t)v0, h1 = (half_t)v1;
      half_t l0 = (half_t)(v0 - (float)h0), l1 = (half_t)(v1 - (float)h1);
      union { half_t h[2]; unsigned int u; } ph, pl;
      ph.h[0] = h0; ph.h[1] = h1;
      pl.h[0] = l0; pl.h[1] = l1;
      *(unsigned int*)(Ohi + (size_t)(n0 + nl) * CP + cp) = ph.u;
      *(unsigned int*)(Olo + (size_t)(n0 + nl) * CP + cp) = pl.u;
    }
  } else {
    half_t* G = gF + (size_t)b * CP * NN;
    #pragma unroll
    for (int fo = 0; fo < 4; ++fo)
      #pragma unroll
      for (int r = 0; r < 4; ++r){
        int o = wo * 64 + fo * 16 + lq * 4 + r;
        #pragma unroll
        for (int fn = 0; fn < 2; ++fn){
          int n = n0 + wn * 32 + fn * 16 + lr;
          G[(size_t)o * NN + n] = (half_t)(acc[fo][fn][r] * 0.0625f);
        }
      }
  }
}

// ---------------- K2: S^T tile + fused col-stats + E(fp16) store ------------
// XCD-swizzled grid.x (1024 = 32x32 tiles); coalesced ST store via LDS bounce.
__global__ __launch_bounds__(256) void s_gemm(
    const half_t* __restrict__ tTh, const half_t* __restrict__ tTl,
    const half_t* __restrict__ pTh, const half_t* __restrict__ pTl,
    half_t* __restrict__ ST, float* __restrict__ pmax,
    float* __restrict__ psum)
{
  const int b  = blockIdx.z;
  // bijective XCD swizzle: each XCD owns 128 consecutive tiles = 4 n-rows x 32 m
  const int bx = blockIdx.x;
  const int tile  = (bx & 7) * 128 + (bx >> 3);
  const int ntile = tile >> 5;
  const int m0 = (tile & 31) * 128;
  const int n0 = ntile * 128;
  const size_t tb = (size_t)b * NN * CP;
  half_t* STb = ST + (size_t)b * NN * NN;
  __shared__ half_t lds[4 * 128 * 64];       // Ah | Al | Bh | Bl, 64 KB
  const int tid = threadIdx.x;
  const int wid = tid >> 6, lane = tid & 63;
  const int wn = wid >> 1, wm = wid & 1;
  const int lr = lane & 15, lq = lane >> 4;

  f32x4 acc[4][4];
  #pragma unroll
  for (int i = 0; i < 4; ++i)
    #pragma unroll
    for (int j = 0; j < 4; ++j) acc[i][j] = (f32x4){0.f,0.f,0.f,0.f};

  const half_t* baseA_h = tTh + tb + (size_t)n0 * CP;
  const half_t* baseA_l = tTl + tb + (size_t)n0 * CP;
  const half_t* baseB_h = pTh + tb + (size_t)m0 * CP;
  const half_t* baseB_l = pTl + tb + (size_t)m0 * CP;

  #pragma unroll 1
  for (int kc = 0; kc < CP; kc += 64){
    #pragma unroll
    for (int it = 0; it < 4; ++it){
      int seg = wid * 4 + it;
      int row = seg * 8 + (lane >> 3);
      int us  = (lane & 7) ^ (row & 7);
      size_t go = (size_t)row * CP + kc + us * 8;
      __builtin_amdgcn_global_load_lds(GPTR(baseA_h + go), LPTR(lds + seg*512), 16, 0, 0);
      __builtin_amdgcn_global_load_lds(GPTR(baseA_l + go), LPTR(lds + 8192 + seg*512), 16, 0, 0);
      __builtin_amdgcn_global_load_lds(GPTR(baseB_h + go), LPTR(lds + 16384 + seg*512), 16, 0, 0);
      __builtin_amdgcn_global_load_lds(GPTR(baseB_l + go), LPTR(lds + 24576 + seg*512), 16, 0, 0);
    }
    asm volatile("s_waitcnt vmcnt(0)" ::: "memory");
    __syncthreads();

    #pragma unroll
    for (int kk = 0; kk < 2; ++kk){
      f16x8 ah[4], al[4], bh[4], bl[4];
      #pragma unroll
      for (int f = 0; f < 4; ++f){
        int rA = wn*64 + f*16 + lr;
        int cA = (kk*32 + lq*8) ^ ((rA & 7) * 8);
        ah[f] = *(const f16x8*)(lds + rA*64 + cA);
        al[f] = *(const f16x8*)(lds + 8192 + rA*64 + cA);
        int rB = wm*64 + f*16 + lr;
        int cB = (kk*32 + lq*8) ^ ((rB & 7) * 8);
        bh[f] = *(const f16x8*)(lds + 16384 + rB*64 + cB);
        bl[f] = *(const f16x8*)(lds + 24576 + rB*64 + cB);
      }
      #pragma unroll
      for (int fn = 0; fn < 4; ++fn)
        #pragma unroll
        for (int fm = 0; fm < 4; ++fm){
          acc[fn][fm] = __builtin_amdgcn_mfma_f32_16x16x32_f16(ah[fn], bh[fm], acc[fn][fm], 0,0,0);
          acc[fn][fm] = __builtin_amdgcn_mfma_f32_16x16x32_f16(al[fn], bh[fm], acc[fn][fm], 0,0,0);
          acc[fn][fm] = __builtin_amdgcn_mfma_f32_16x16x32_f16(ah[fn], bl[fm], acc[fn][fm], 0,0,0);
        }
    }
    __syncthreads();
  }

  // ---- fused column-stats epilogue + coalesced E store ----
  float*  red  = (float*)lds;          // 256 f
  float*  red2 = (float*)lds + 256;    // 256 f
  half_t* Eb   = lds + 2048;           // bounce [128][132] halfs (33.8 KB)

  float cmax[4];
  #pragma unroll
  for (int fm = 0; fm < 4; ++fm){
    float t = -3.0e38f;
    #pragma unroll
    for (int fn = 0; fn < 4; ++fn)
      #pragma unroll
      for (int r = 0; r < 4; ++r) t = fmaxf(t, acc[fn][fm][r]);
    t = fmaxf(t, __shfl_xor(t, 16, 64));
    t = fmaxf(t, __shfl_xor(t, 32, 64));
    cmax[fm] = t;
  }
  if (lq == 0){
    #pragma unroll
    for (int fm = 0; fm < 4; ++fm) red[(wid*4+fm)*16 + lr] = cmax[fm];
  }
  __syncthreads();
  #pragma unroll
  for (int fm = 0; fm < 4; ++fm)
    cmax[fm] = fmaxf(red[((wm)*4+fm)*16 + lr], red[((2+wm)*4+fm)*16 + lr]);

  float csum[4] = {0.f, 0.f, 0.f, 0.f};
  #pragma unroll
  for (int fn = 0; fn < 4; ++fn)
    #pragma unroll
    for (int r = 0; r < 4; ++r){
      int nl = wn*64 + fn*16 + lq*4 + r;
      half_t* db = Eb + nl*132 + wm*64;
      #pragma unroll
      for (int fm = 0; fm < 4; ++fm){
        float e = __expf(acc[fn][fm][r] - cmax[fm]);
        csum[fm] += e;
        db[fm*16 + lr] = (half_t)e;
      }
    }
  #pragma unroll
  for (int fm = 0; fm < 4; ++fm){
    csum[fm] += __shfl_xor(csum[fm], 16, 64);
    csum[fm] += __shfl_xor(csum[fm], 32, 64);
  }
  if (lq == 0){
    #pragma unroll
    for (int fm = 0; fm < 4; ++fm) red2[(wid*4+fm)*16 + lr] = csum[fm];
  }
  __syncthreads();

  // coalesced 16B-row store of the 128x128 E tile
  #pragma unroll
  for (int it = 0; it < 8; ++it){
    int idx = tid + it * 256;            // 2048 chunks
    int row = idx >> 4;
    int ch  = idx & 15;
    uint4 v = *(const uint4*)(Eb + row*132 + ch*8);
    *(uint4*)(STb + (size_t)(n0 + row) * NN + m0 + ch*8) = v;
  }
  if (wn == 0 && lq == 0){
    #pragma unroll
    for (int fm = 0; fm < 4; ++fm){
      int m = m0 + wm*64 + fm*16 + lr;
      pmax[((size_t)b * NT + ntile) * NN + m] = cmax[fm];
      psum[((size_t)b * NT + ntile) * NN + m] = red2[((wm)*4+fm)*16 + lr]
                                              + red2[((2+wm)*4+fm)*16 + lr];
    }
  }
}

// ---------------- K3: merge tile partials -> corr[b][nt][m] -----------------
__global__ __launch_bounds__(256) void merge_corr(
    const float* __restrict__ pmax, const float* __restrict__ psum,
    float* __restrict__ corr)
{
  const size_t base = (size_t)blockIdx.y * NT * NN;
  const int m = blockIdx.x * 256 + threadIdx.x;
  float pm[NT];
  float mx = -3.0e38f;
  #pragma unroll
  for (int nt = 0; nt < NT; ++nt){
    pm[nt] = pmax[base + (size_t)nt * NN + m];
    mx = fmaxf(mx, pm[nt]);
  }
  float den = 0.f;
  #pragma unroll
  for (int nt = 0; nt < NT; ++nt){
    pm[nt] = __expf(pm[nt] - mx);
    den += psum[base + (size_t)nt * NN + m] * pm[nt];
  }
  const float r = 1.f / den;
  #pragma unroll
  for (int nt = 0; nt < NT; ++nt)
    corr[base + (size_t)nt * NN + m] = pm[nt] * r;
}

// ---------------- K4: yp[b][ks][c][n] = sum_m g[c][m]*(E[n][m]*corr) --------
// XCD-swizzled 1D grid; ST/corr reg-prefetch one stage ahead (issue under MFMA)
__global__ __launch_bounds__(256) void y_gemm(
    const half_t* __restrict__ gF, const half_t* __restrict__ ST,
    const float* __restrict__ corr, float* __restrict__ yp)
{
  const int bx  = blockIdx.x;
  const int lin = (bx & 7) * 128 + (bx >> 3);
  const int b   = lin >> 8;
  const int rem = lin & 255;
  const int ks  = rem >> 6;
  const int nx  = rem & 63;
  const int n0  = nx * 64;
  const int nt  = nx >> 1;
  const half_t* G   = gF + (size_t)b * CP * NN;
  const half_t* STb = ST + (size_t)b * NN * NN;
  const float* corb = corr + ((size_t)b * NT + nt) * NN;
  __shared__ half_t As[128*64];
  __shared__ half_t Bs[64*64];
  const int tid = threadIdx.x;
  const int wid = tid >> 6, lane = tid & 63;
  const int wc = wid >> 1, wn = wid & 1;
  const int lr = lane & 15, lq = lane >> 4;

  f32x4 acc[4][2];
  #pragma unroll
  for (int i = 0; i < 4; ++i)
    #pragma unroll
    for (int j = 0; j < 2; ++j) acc[i][j] = (f32x4){0.f,0.f,0.f,0.f};

  uint2 evA[4]; float4 crA[4];
  uint2 evB[4]; float4 crB[4];

  // prologue: load regs for st = 0
  {
    const int mc = ks * (NN / KSL);
    #pragma unroll
    for (int i = 0; i < 4; ++i){
      int idx = tid + i * 256;
      int r = idx >> 4, q = idx & 15;
      int mm = mc + q * 4;
      evA[i] = *(const uint2*)(STb + (size_t)(n0 + r) * NN + mm);
      crA[i] = *(const float4*)(corb + mm);
    }
  }

#define Y_STEP(ST_IDX, CEV, CCR, NEV, NCR)                                     \
  {                                                                            \
    const int st = (ST_IDX);                                                   \
    const int mc = ks * (NN / KSL) + st * 64;                                  \
    _Pragma("unroll")                                                          \
    for (int it = 0; it < 4; ++it){                                            \
      int seg = wid * 4 + it;                                                  \
      int row = seg * 8 + (lane >> 3);                                         \
      int us  = (lane & 7) ^ (row & 7);                                        \
      __builtin_amdgcn_global_load_lds(GPTR(G + (size_t)row * NN + mc + us*8), \
                                       LPTR(As + seg*512), 16, 0, 0);          \
    }                                                                          \
    _Pragma("unroll")                                                          \
    for (int i = 0; i < 4; ++i){                                               \
      int idx = tid + i * 256;                                                 \
      int r = idx >> 4;                                                        \
      int q = idx & 15;                                                        \
      union { half_t h[4]; uint2 u2; } ev, eo;                                 \
      ev.u2 = CEV[i];                                                          \
      float4 cr = CCR[i];                                                      \
      eo.h[0] = (half_t)((float)ev.h[0] * cr.x);                               \
      eo.h[1] = (half_t)((float)ev.h[1] * cr.y);                               \
      eo.h[2] = (half_t)((float)ev.h[2] * cr.z);                               \
      eo.h[3] = (half_t)((float)ev.h[3] * cr.w);                               \
      int c4 = (q * 4) ^ ((r & 7) * 8);                                        \
      *(uint2*)(Bs + r * 64 + c4) = eo.u2;                                     \
    }                                                                          \
    asm volatile("s_waitcnt vmcnt(0)" ::: "memory");                           \
    __syncthreads();                                                           \
    {                                                                          \
      const int pst = (st < 15) ? st + 1 : 15;                                 \
      const int pmc = ks * (NN / KSL) + pst * 64;                              \
      _Pragma("unroll")                                                        \
      for (int i = 0; i < 4; ++i){                                             \
        int idx = tid + i * 256;                                               \
        int r = idx >> 4, q = idx & 15;                                        \
        int mm = pmc + q * 4;                                                  \
        NEV[i] = *(const uint2*)(STb + (size_t)(n0 + r) * NN + mm);            \
        NCR[i] = *(const float4*)(corb + mm);                                  \
      }                                                                        \
    }                                                                          \
    _Pragma("unroll")                                                          \
    for (int kk = 0; kk < 2; ++kk){                                            \
      f16x8 af[4], bf[2];                                                      \
      _Pragma("unroll")                                                        \
      for (int f = 0; f < 4; ++f){                                             \
        int rA = wc*64 + f*16 + lr;                                            \
        af[f] = *(const f16x8*)(As + rA*64 + ((kk*32 + lq*8) ^ ((rA & 7)*8))); \
      }                                                                        \
      _Pragma("unroll")                                                        \
      for (int f = 0; f < 2; ++f){                                             \
        int rB = wn*32 + f*16 + lr;                                            \
        bf[f] = *(const f16x8*)(Bs + rB*64 + ((kk*32 + lq*8) ^ ((rB & 7)*8))); \
      }                                                                        \
      _Pragma("unroll")                                                        \
      for (int fc = 0; fc < 4; ++fc)                                           \
        _Pragma("unroll")                                                      \
        for (int fn = 0; fn < 2; ++fn)                                         \
          acc[fc][fn] = __builtin_amdgcn_mfma_f32_16x16x32_f16(                \
              af[fc], bf[fn], acc[fc][fn], 0,0,0);                             \
    }                                                                          \
    __syncthreads();                                                           \
  }

  #pragma unroll 1
  for (int sp = 0; sp < 8; ++sp){
    Y_STEP(2*sp,     evA, crA, evB, crB)
    Y_STEP(2*sp + 1, evB, crB, evA, crA)
  }
#undef Y_STEP

  #pragma unroll
  for (int fc = 0; fc < 4; ++fc)
    #pragma unroll
    for (int r = 0; r < 4; ++r){
      int c = wc*64 + fc*16 + lq*4 + r;
      float* dst = yp + (((size_t)b * KSL + ks) * CP + c) * NN + n0;
      #pragma unroll
      for (int fn = 0; fn < 2; ++fn) dst[wn*32 + fn*16 + lr] = acc[fc][fn][r];
    }
}

// ---------------- K5: z = Wz @ y (fp32; sums the KSL partials in staging) ---
__global__ __launch_bounds__(256) void z_gemm(
    const float* __restrict__ Wz, const float* __restrict__ yp,
    float* __restrict__ z)
{
  const int b  = blockIdx.z;
  const int o0 = blockIdx.y * 128;
  const int n0 = blockIdx.x * 64;
  const float* y0 = yp + ((size_t)b * KSL + 0) * CP * NN;
  const float* y1 = yp + ((size_t)b * KSL + 1) * CP * NN;
  const float* y2 = yp + ((size_t)b * KSL + 2) * CP * NN;
  const float* y3 = yp + ((size_t)b * KSL + 3) * CP * NN;
  float* zb = z + (size_t)b * CIN * NN;

  __shared__ float a_s[32][132];
  __shared__ float b_s[32][64];

  const int tid = threadIdx.x;
  const int tx = tid & 15, ty = tid >> 4;

  float acc[2][4][4];
  #pragma unroll
  for (int qa = 0; qa < 2; ++qa)
    #pragma unroll
    for (int i = 0; i < 4; ++i)
      #pragma unroll
      for (int j = 0; j < 4; ++j) acc[qa][i][j] = 0.f;

  for (int k0 = 0; k0 < CP; k0 += 32){
    #pragma unroll
    for (int i = 0; i < 4; ++i){
      int f4i = tid + i * 256;
      int c  = f4i >> 3;
      int k4 = f4i & 7;
      float4 w = *(const float4*)(Wz + (size_t)(o0 + c) * CP + k0 + k4 * 4);
      a_s[k4*4+0][c] = w.x;
      a_s[k4*4+1][c] = w.y;
      a_s[k4*4+2][c] = w.z;
      a_s[k4*4+3][c] = w.w;
    }
    #pragma unroll
    for (int i = 0; i < 2; ++i){
      int f4i = tid + i * 256;
      int kk = f4i >> 4;
      int n4 = f4i & 15;
      const size_t off = (size_t)(k0 + kk) * NN + n0 + n4 * 4;
      float4 v0 = *(const float4*)(y0 + off);
      float4 v1 = *(const float4*)(y1 + off);
      float4 v2 = *(const float4*)(y2 + off);
      float4 v3 = *(const float4*)(y3 + off);
      float4 sv;
      sv.x = v0.x + v1.x + v2.x + v3.x;
      sv.y = v0.y + v1.y + v2.y + v3.y;
      sv.z = v0.z + v1.z + v2.z + v3.z;
      sv.w = v0.w + v1.w + v2.w + v3.w;
      *(float4*)&b_s[kk][n4*4] = sv;
    }
    __syncthreads();
    #pragma unroll
    for (int kk = 0; kk < 32; ++kk){
      float af[8], bf[4];
      *(float4*)&af[0] = *(const float4*)&a_s[kk][ty*4];
      *(float4*)&af[4] = *(const float4*)&a_s[kk][ty*4+64];
      *(float4*)&bf[0] = *(const float4*)&b_s[kk][tx*4];
      #pragma unroll
      for (int qa = 0; qa < 2; ++qa)
        #pragma unroll
        for (int i = 0; i < 4; ++i)
          #pragma unroll
          for (int j = 0; j < 4; ++j)
            acc[qa][i][j] = fmaf(af[qa*4+i], bf[j], acc[qa][i][j]);
    }
    __syncthreads();
  }
  #pragma unroll
  for (int qa = 0; qa < 2; ++qa)
    #pragma unroll
    for (int i = 0; i < 4; ++i){
      const int row = o0 + qa*64 + ty*4 + i;
      float4 v = make_float4(acc[qa][i][0], acc[qa][i][1],
                             acc[qa][i][2], acc[qa][i][3]);
      *(float4*)(zb + (size_t)row * NN + n0 + tx*4) = v;
    }
}

// ---------------- K6: BatchNorm batch stats ---------------------------------
__global__ __launch_bounds__(256) void bn_stats(
    const float* __restrict__ z, float* __restrict__ mean,
    float* __restrict__ rstd)
{
  const int c = blockIdx.x;
  const int tid = threadIdx.x;
  float s = 0.f, s2 = 0.f;
  for (int b = 0; b < B_SZ; ++b){
    const float4* row = (const float4*)(z + ((size_t)b * CIN + c) * NN);
    #pragma unroll
    for (int i = 0; i < 4; ++i){
      float4 v = row[tid + i*256];
      s  += v.x + v.y + v.z + v.w;
      s2 += v.x*v.x + v.y*v.y + v.z*v.z + v.w*v.w;
    }
  }
  s  = wave_sum64(s);
  s2 = wave_sum64(s2);
  __shared__ float rs[4];
  __shared__ float rq[4];
  const int wid = tid >> 6, lane = tid & 63;
  if (lane == 0){ rs[wid] = s; rq[wid] = s2; }
  __syncthreads();
  if (tid == 0){
    const float S1 = rs[0]+rs[1]+rs[2]+rs[3];
    const float S2 = rq[0]+rq[1]+rq[2]+rq[3];
    const float inv = 1.f / (float)(B_SZ * NN);
    const float m = S1 * inv;
    const float var = S2 * inv - m * m;
    mean[c] = m;
    rstd[c] = 1.f / sqrtf(var + 1e-5f);
  }
}

// ---------------- K7: out = (z-mean)*rstd*gamma + beta + x ------------------
__global__ __launch_bounds__(256) void finalize_k(
    const float* __restrict__ z, const float* __restrict__ x,
    const float* __restrict__ mean, const float* __restrict__ rstd,
    const float* __restrict__ gamma, const float* __restrict__ beta,
    float* __restrict__ out)
{
  const int total = B_SZ * CIN * NN / 4;
  for (int i = blockIdx.x * blockDim.x + threadIdx.x; i < total;
       i += gridDim.x * blockDim.x){
    const int c = (i >> 10) & (CIN - 1);
    float4 zv = ((const float4*)z)[i];
    float4 xv = ((const float4*)x)[i];
    const float m = mean[c], r = rstd[c], ga = gamma[c], be = beta[c];
    float4 o;
    o.x = (zv.x - m) * r * ga + be + xv.x;
    o.y = (zv.y - m) * r * ga + be + xv.y;
    o.z = (zv.z - m) * r * ga + be + xv.z;
    o.w = (zv.w - m) * r * ga + be + xv.w;
    ((float4*)out)[i] = o;
  }
}

// ---------------- launcher --------------------------------------------------
extern "C" void kernel_launch(void* const* d_in, const int* in_sizes, int n_in,
                              void* d_out, int out_size, void* d_ws, size_t ws_size,
                              hipStream_t stream)
{
  const float* x     = (const float*)d_in[0];
  const float* Wt    = (const float*)d_in[1];
  const float* Wp    = (const float*)d_in[2];
  const float* Wg    = (const float*)d_in[3];
  const float* Wz    = (const float*)d_in[4];
  const float* gamma = (const float*)d_in[5];
  const float* beta  = (const float*)d_in[6];
  float* out = (float*)d_out;

  float* wsf = (float*)d_ws;
  size_t off = 0;
  half_t* ST  = (half_t*)(wsf + off); off += (size_t)B_SZ * NN * NN / 2;   // 134MB
  half_t* tTh = (half_t*)(wsf + off); off += (size_t)B_SZ*NN*CP/2;
  half_t* tTl = (half_t*)(wsf + off); off += (size_t)B_SZ*NN*CP/2;
  half_t* pTh = (half_t*)(wsf + off); off += (size_t)B_SZ*NN*CP/2;
  half_t* pTl = (half_t*)(wsf + off); off += (size_t)B_SZ*NN*CP/2;
  half_t* gF  = (half_t*)(wsf + off); off += (size_t)B_SZ*CP*NN/2;
  half_t* xTh = (half_t*)(wsf + off); off += (size_t)B_SZ*NN*CIN/2;
  half_t* xTl = (half_t*)(wsf + off); off += (size_t)B_SZ*NN*CIN/2;
  half_t* Wh  = (half_t*)(wsf + off); off += (size_t)3*CP*CIN/2;
  half_t* Wl  = (half_t*)(wsf + off); off += (size_t)3*CP*CIN/2;
  float*  yp  = wsf + off; off += (size_t)B_SZ * KSL * CP * NN;            // 33.5MB
  float*  pmax= wsf + off; off += (size_t)B_SZ * NT * NN;
  float*  psum= wsf + off; off += (size_t)B_SZ * NT * NN;
  float*  corr= wsf + off; off += (size_t)B_SZ * NT * NN;
  float*  meanb = wsf + off; off += CIN;
  float*  rstdb = wsf + off; off += CIN;
  float*  z = (float*)ST;   // alias: ST dead after y_gemm

  split_w <<<dim3(3, 4),           256, 0, stream>>>(Wt, Wp, Wg, Wh, Wl);
  split_x <<<dim3(64, 4, B_SZ),    256, 0, stream>>>(x, xTh, xTl);
  tpg_gemm<<<dim3(64, 3, B_SZ),    256, 0, stream>>>(Wh, Wl, xTh, xTl,
                                                     tTh, tTl, pTh, pTl, gF);
  s_gemm    <<<dim3(1024, 1, B_SZ),256, 0, stream>>>(tTh, tTl, pTh, pTl,
                                                     ST, pmax, psum);
  merge_corr<<<dim3(16, B_SZ),     256, 0, stream>>>(pmax, psum, corr);
  y_gemm    <<<dim3(1024),         256, 0, stream>>>(gF, ST, corr, yp);
  z_gemm    <<<dim3(64, 2, B_SZ),  256, 0, stream>>>(Wz, yp, z);
  bn_stats  <<<dim3(CIN),          256, 0, stream>>>(z, meanb, rstdb);
  finalize_k<<<dim3(2048),         256, 0, stream>>>(z, x, meanb, rstdb,
                                                     gamma, beta, out);
}

// Round 8
// 230.018 us; speedup vs baseline: 1.1951x; 1.1951x over previous
//
#include <hip/hip_runtime.h>
#include <hip/hip_fp16.h>

#define B_SZ 4
#define CIN  256
#define CP   128
#define NN   4096
#define NT   32          // 128-row n-tiles per batch (softmax partials)
#define KSL  4           // k-slices in y_gemm (K=1024 each)

typedef _Float16 half_t;
typedef _Float16 f16x8 __attribute__((ext_vector_type(8)));
typedef float f32x4 __attribute__((ext_vector_type(4)));

#define GPTR(p) ((const __attribute__((address_space(1))) void*)(p))
#define LPTR(p) ((__attribute__((address_space(3))) void*)(p))

__device__ __forceinline__ float wave_sum64(float v){
  #pragma unroll
  for (int o = 32; o > 0; o >>= 1) v += __shfl_xor(v, o, 64);
  return v;
}

// ---------------- K0a: split W*16 into fp16 hi/lo ---------------------------
__global__ __launch_bounds__(256) void split_w(
    const float* __restrict__ Wt, const float* __restrict__ Wp,
    const float* __restrict__ Wg, half_t* __restrict__ Wh,
    half_t* __restrict__ Wl)
{
  const int sel = blockIdx.x;
  const float* W = (sel == 0) ? Wt : ((sel == 1) ? Wp : Wg);
  half_t* oh = Wh + sel * (CP * CIN);
  half_t* ol = Wl + sel * (CP * CIN);
  #pragma unroll
  for (int i = 0; i < 8; ++i){
    int i4 = blockIdx.y * 2048 + threadIdx.x + i * 256;
    float4 v = ((const float4*)W)[i4];
    v.x *= 16.f; v.y *= 16.f; v.z *= 16.f; v.w *= 16.f;
    union { half_t h[4]; uint2 u; } hh, ll;
    hh.h[0] = (half_t)v.x; ll.h[0] = (half_t)(v.x - (float)hh.h[0]);
    hh.h[1] = (half_t)v.y; ll.h[1] = (half_t)(v.y - (float)hh.h[1]);
    hh.h[2] = (half_t)v.z; ll.h[2] = (half_t)(v.z - (float)hh.h[2]);
    hh.h[3] = (half_t)v.w; ll.h[3] = (half_t)(v.w - (float)hh.h[3]);
    *(uint2*)(oh + i4 * 4) = hh.u;
    *(uint2*)(ol + i4 * 4) = ll.u;
  }
}

// ---------------- K0b: transpose-split x -> xT hi/lo [b][n][c] --------------
__global__ __launch_bounds__(256) void split_x(
    const float* __restrict__ x, half_t* __restrict__ xTh,
    half_t* __restrict__ xTl)
{
  const int b  = blockIdx.z;
  const int c0 = blockIdx.y * 64;
  const int n0 = blockIdx.x * 64;
  __shared__ float lds[64][68];
  const int tid = threadIdx.x;
  #pragma unroll
  for (int i = 0; i < 4; ++i){
    int idx = tid + i * 256;
    int cr = idx >> 4, nq = idx & 15;
    float4 v = *(const float4*)(x + ((size_t)b * CIN + c0 + cr) * NN + n0 + nq * 4);
    *(float4*)&lds[cr][nq * 4] = v;
  }
  __syncthreads();
  #pragma unroll
  for (int i = 0; i < 8; ++i){
    int idx = tid + i * 256;
    int nl = idx >> 5;
    int cp = (idx & 31) * 2;
    float v0 = lds[cp][nl], v1 = lds[cp + 1][nl];
    half_t h0 = (half_t)v0, h1 = (half_t)v1;
    half_t l0 = (half_t)(v0 - (float)h0), l1 = (half_t)(v1 - (float)h1);
    union { half_t h[2]; unsigned int u; } ph, pl;
    ph.h[0] = h0; ph.h[1] = h1;
    pl.h[0] = l0; pl.h[1] = l1;
    size_t o = ((size_t)b * NN + n0 + nl) * CIN + c0 + cp;
    *(unsigned int*)(xTh + o) = ph.u;
    *(unsigned int*)(xTl + o) = pl.u;
  }
}

// ---------------- K1: t/p/g via fp16 3-slab MFMA ----------------------------
__global__ __launch_bounds__(256) void tpg_gemm(
    const half_t* __restrict__ Wh, const half_t* __restrict__ Wl,
    const half_t* __restrict__ xTh, const half_t* __restrict__ xTl,
    half_t* __restrict__ tTh, half_t* __restrict__ tTl,
    half_t* __restrict__ pTh, half_t* __restrict__ pTl,
    half_t* __restrict__ gF)
{
  const int b   = blockIdx.z;
  const int sel = blockIdx.y;
  const int n0  = blockIdx.x * 64;
  const half_t* Ah_g = Wh + sel * (CP * CIN);
  const half_t* Al_g = Wl + sel * (CP * CIN);
  const half_t* Bh_g = xTh + ((size_t)b * NN + n0) * CIN;
  const half_t* Bl_g = xTl + ((size_t)b * NN + n0) * CIN;

  __shared__ half_t lds[24576];   // Ah 0 | Al 8192 | Bh 16384 | Bl 20480
  const int tid = threadIdx.x;
  const int wid = tid >> 6, lane = tid & 63;
  const int wo = wid >> 1, wn = wid & 1;
  const int lr = lane & 15, lq = lane >> 4;

  f32x4 acc[4][2];
  #pragma unroll
  for (int i = 0; i < 4; ++i)
    #pragma unroll
    for (int j = 0; j < 2; ++j) acc[i][j] = (f32x4){0.f,0.f,0.f,0.f};

  #pragma unroll 1
  for (int kc = 0; kc < CIN; kc += 64){
    #pragma unroll
    for (int it = 0; it < 4; ++it){
      int seg = wid * 4 + it;
      int row = seg * 8 + (lane >> 3);
      int us  = (lane & 7) ^ (row & 7);
      size_t go = (size_t)row * CIN + kc + us * 8;
      __builtin_amdgcn_global_load_lds(GPTR(Ah_g + go), LPTR(lds + seg*512), 16, 0, 0);
      __builtin_amdgcn_global_load_lds(GPTR(Al_g + go), LPTR(lds + 8192 + seg*512), 16, 0, 0);
    }
    #pragma unroll
    for (int it = 0; it < 2; ++it){
      int seg = wid * 2 + it;
      int row = seg * 8 + (lane >> 3);
      int us  = (lane & 7) ^ (row & 7);
      size_t go = (size_t)row * CIN + kc + us * 8;
      __builtin_amdgcn_global_load_lds(GPTR(Bh_g + go), LPTR(lds + 16384 + seg*512), 16, 0, 0);
      __builtin_amdgcn_global_load_lds(GPTR(Bl_g + go), LPTR(lds + 20480 + seg*512), 16, 0, 0);
    }
    asm volatile("s_waitcnt vmcnt(0)" ::: "memory");
    __syncthreads();

    #pragma unroll
    for (int kk = 0; kk < 2; ++kk){
      f16x8 ah[4], al4[4], bh[2], bl[2];
      #pragma unroll
      for (int f = 0; f < 4; ++f){
        int rA = wo * 64 + f * 16 + lr;
        int cA = (kk*32 + lq*8) ^ ((rA & 7) * 8);
        ah[f]  = *(const f16x8*)(lds + rA * 64 + cA);
        al4[f] = *(const f16x8*)(lds + 8192 + rA * 64 + cA);
      }
      #pragma unroll
      for (int f = 0; f < 2; ++f){
        int rB = wn * 32 + f * 16 + lr;
        int cB = (kk*32 + lq*8) ^ ((rB & 7) * 8);
        bh[f] = *(const f16x8*)(lds + 16384 + rB * 64 + cB);
        bl[f] = *(const f16x8*)(lds + 20480 + rB * 64 + cB);
      }
      #pragma unroll
      for (int fo = 0; fo < 4; ++fo)
        #pragma unroll
        for (int fn = 0; fn < 2; ++fn){
          acc[fo][fn] = __builtin_amdgcn_mfma_f32_16x16x32_f16(ah[fo],  bh[fn], acc[fo][fn], 0,0,0);
          acc[fo][fn] = __builtin_amdgcn_mfma_f32_16x16x32_f16(al4[fo], bh[fn], acc[fo][fn], 0,0,0);
          acc[fo][fn] = __builtin_amdgcn_mfma_f32_16x16x32_f16(ah[fo],  bl[fn], acc[fo][fn], 0,0,0);
        }
    }
    __syncthreads();
  }

  if (sel < 2){
    half_t* Ohi = ((sel == 0) ? tTh : pTh) + (size_t)b * NN * CP;
    half_t* Olo = ((sel == 0) ? tTl : pTl) + (size_t)b * NN * CP;
    float (*ldsT)[132] = (float (*)[132])lds;
    #pragma unroll
    for (int fo = 0; fo < 4; ++fo)
      #pragma unroll
      for (int fn = 0; fn < 2; ++fn)
        #pragma unroll
        for (int r = 0; r < 4; ++r){
          int n = wn * 32 + fn * 16 + lr;
          int o = wo * 64 + fo * 16 + lq * 4 + r;
          ldsT[n][o] = acc[fo][fn][r] * 0.0625f;
        }
    __syncthreads();
    #pragma unroll
    for (int it = 0; it < 16; ++it){
      int idx = tid + it * 256;
      int nl = idx >> 6;
      int cp = (idx & 63) * 2;
      float v0 = ldsT[nl][cp], v1 = ldsT[nl][cp + 1];
      half_t h0 = (half_t)v0, h1 = (half_t)v1;
      union { half_t h[2]; unsigned int u; } ph;
      ph.h[0] = h0; ph.h[1] = h1;
      *(unsigned int*)(Ohi + (size_t)(n0 + nl) * CP + cp) = ph.u;
      if (sel == 0){   // only t's lo is consumed (2-slab s_gemm drops p-lo)
        half_t l0 = (half_t)(v0 - (float)h0), l1 = (half_t)(v1 - (float)h1);
        union { half_t h[2]; unsigned int u; } pl;
        pl.h[0] = l0; pl.h[1] = l1;
        *(unsigned int*)(Olo + (size_t)(n0 + nl) * CP + cp) = pl.u;
      }
    }
  } else {
    half_t* G = gF + (size_t)b * CP * NN;
    #pragma unroll
    for (int fo = 0; fo < 4; ++fo)
      #pragma unroll
      for (int r = 0; r < 4; ++r){
        int o = wo * 64 + fo * 16 + lq * 4 + r;
        #pragma unroll
        for (int fn = 0; fn < 2; ++fn){
          int n = n0 + wn * 32 + fn * 16 + lr;
          G[(size_t)o * NN + n] = (half_t)(acc[fo][fn][r] * 0.0625f);
        }
      }
  }
}

// ---------------- K2: S^T tile + fused col-stats + E(fp16) store ------------
// 2-slab: S = th*ph + tl*ph (drops th*pl; ~0.006 logit err, negligible).
__global__ __launch_bounds__(256) void s_gemm(
    const half_t* __restrict__ tTh, const half_t* __restrict__ tTl,
    const half_t* __restrict__ pTh,
    half_t* __restrict__ ST, float* __restrict__ pmax,
    float* __restrict__ psum)
{
  const int b  = blockIdx.z;
  const int m0 = blockIdx.x * 128;
  const int n0 = blockIdx.y * 128;
  const size_t tb = (size_t)b * NN * CP;
  half_t* STb = ST + (size_t)b * NN * NN;
  __shared__ half_t lds[3 * 128 * 64];       // Ah | Al | Bh, 48 KB
  const int tid = threadIdx.x;
  const int wid = tid >> 6, lane = tid & 63;
  const int wn = wid >> 1, wm = wid & 1;
  const int lr = lane & 15, lq = lane >> 4;

  f32x4 acc[4][4];
  #pragma unroll
  for (int i = 0; i < 4; ++i)
    #pragma unroll
    for (int j = 0; j < 4; ++j) acc[i][j] = (f32x4){0.f,0.f,0.f,0.f};

  const half_t* baseA_h = tTh + tb + (size_t)n0 * CP;
  const half_t* baseA_l = tTl + tb + (size_t)n0 * CP;
  const half_t* baseB_h = pTh + tb + (size_t)m0 * CP;

  #pragma unroll 1
  for (int kc = 0; kc < CP; kc += 64){
    #pragma unroll
    for (int it = 0; it < 4; ++it){
      int seg = wid * 4 + it;
      int row = seg * 8 + (lane >> 3);
      int us  = (lane & 7) ^ (row & 7);
      size_t go = (size_t)row * CP + kc + us * 8;
      __builtin_amdgcn_global_load_lds(GPTR(baseA_h + go), LPTR(lds + seg*512), 16, 0, 0);
      __builtin_amdgcn_global_load_lds(GPTR(baseA_l + go), LPTR(lds + 8192 + seg*512), 16, 0, 0);
      __builtin_amdgcn_global_load_lds(GPTR(baseB_h + go), LPTR(lds + 16384 + seg*512), 16, 0, 0);
    }
    asm volatile("s_waitcnt vmcnt(0)" ::: "memory");
    __syncthreads();

    #pragma unroll
    for (int kk = 0; kk < 2; ++kk){
      f16x8 ah[4], al[4], bh[4];
      #pragma unroll
      for (int f = 0; f < 4; ++f){
        int rA = wn*64 + f*16 + lr;
        int cA = (kk*32 + lq*8) ^ ((rA & 7) * 8);
        ah[f] = *(const f16x8*)(lds + rA*64 + cA);
        al[f] = *(const f16x8*)(lds + 8192 + rA*64 + cA);
        int rB = wm*64 + f*16 + lr;
        int cB = (kk*32 + lq*8) ^ ((rB & 7) * 8);
        bh[f] = *(const f16x8*)(lds + 16384 + rB*64 + cB);
      }
      #pragma unroll
      for (int fn = 0; fn < 4; ++fn)
        #pragma unroll
        for (int fm = 0; fm < 4; ++fm){
          acc[fn][fm] = __builtin_amdgcn_mfma_f32_16x16x32_f16(ah[fn], bh[fm], acc[fn][fm], 0,0,0);
          acc[fn][fm] = __builtin_amdgcn_mfma_f32_16x16x32_f16(al[fn], bh[fm], acc[fn][fm], 0,0,0);
        }
    }
    __syncthreads();
  }

  // ---- fused column-stats epilogue ----
  float* red  = (float*)lds;
  float* red2 = (float*)lds + 256;

  float cmax[4];
  #pragma unroll
  for (int fm = 0; fm < 4; ++fm){
    float t = -3.0e38f;
    #pragma unroll
    for (int fn = 0; fn < 4; ++fn)
      #pragma unroll
      for (int r = 0; r < 4; ++r) t = fmaxf(t, acc[fn][fm][r]);
    t = fmaxf(t, __shfl_xor(t, 16, 64));
    t = fmaxf(t, __shfl_xor(t, 32, 64));
    cmax[fm] = t;
  }
  if (lq == 0){
    #pragma unroll
    for (int fm = 0; fm < 4; ++fm) red[(wid*4+fm)*16 + lr] = cmax[fm];
  }
  __syncthreads();
  #pragma unroll
  for (int fm = 0; fm < 4; ++fm)
    cmax[fm] = fmaxf(red[((wm)*4+fm)*16 + lr], red[((2+wm)*4+fm)*16 + lr]);

  float csum[4] = {0.f, 0.f, 0.f, 0.f};
  #pragma unroll
  for (int fn = 0; fn < 4; ++fn)
    #pragma unroll
    for (int r = 0; r < 4; ++r){
      int n = n0 + wn*64 + fn*16 + lq*4 + r;
      half_t* dst = STb + (size_t)n * NN + m0 + wm*64;
      #pragma unroll
      for (int fm = 0; fm < 4; ++fm){
        float e = __expf(acc[fn][fm][r] - cmax[fm]);
        csum[fm] += e;
        dst[fm*16 + lr] = (half_t)e;
      }
    }
  #pragma unroll
  for (int fm = 0; fm < 4; ++fm){
    csum[fm] += __shfl_xor(csum[fm], 16, 64);
    csum[fm] += __shfl_xor(csum[fm], 32, 64);
  }
  __syncthreads();
  if (lq == 0){
    #pragma unroll
    for (int fm = 0; fm < 4; ++fm) red2[(wid*4+fm)*16 + lr] = csum[fm];
  }
  __syncthreads();
  if (wn == 0 && lq == 0){
    #pragma unroll
    for (int fm = 0; fm < 4; ++fm){
      int m = m0 + wm*64 + fm*16 + lr;
      pmax[((size_t)b * NT + blockIdx.y) * NN + m] = cmax[fm];
      psum[((size_t)b * NT + blockIdx.y) * NN + m] = red2[((wm)*4+fm)*16 + lr]
                                                   + red2[((2+wm)*4+fm)*16 + lr];
    }
  }
}

// ---------------- K3: merge tile partials -> corr[b][nt][m] -----------------
__global__ __launch_bounds__(256) void merge_corr(
    const float* __restrict__ pmax, const float* __restrict__ psum,
    float* __restrict__ corr)
{
  const size_t base = (size_t)blockIdx.y * NT * NN;
  const int m = blockIdx.x * 256 + threadIdx.x;
  float pm[NT];
  float mx = -3.0e38f;
  #pragma unroll
  for (int nt = 0; nt < NT; ++nt){
    pm[nt] = pmax[base + (size_t)nt * NN + m];
    mx = fmaxf(mx, pm[nt]);
  }
  float den = 0.f;
  #pragma unroll
  for (int nt = 0; nt < NT; ++nt){
    pm[nt] = __expf(pm[nt] - mx);
    den += psum[base + (size_t)nt * NN + m] * pm[nt];
  }
  const float r = 1.f / den;
  #pragma unroll
  for (int nt = 0; nt < NT; ++nt)
    corr[base + (size_t)nt * NN + m] = pm[nt] * r;
}

// ---------------- K4: yp[b][ks][c][n] = sum_m g[c][m]*(E[n][m]*corr) --------
__global__ __launch_bounds__(256) void y_gemm(
    const half_t* __restrict__ gF, const half_t* __restrict__ ST,
    const float* __restrict__ corr, float* __restrict__ yp)
{
  const int b  = blockIdx.z;
  const int n0 = blockIdx.x * 64;
  const int nt = blockIdx.x >> 1;
  const int ks = blockIdx.y;
  const half_t* G   = gF + (size_t)b * CP * NN;
  const half_t* STb = ST + (size_t)b * NN * NN;
  const float* corb = corr + ((size_t)b * NT + nt) * NN;
  __shared__ half_t As[128*64];
  __shared__ half_t Bs[64*64];
  const int tid = threadIdx.x;
  const int wid = tid >> 6, lane = tid & 63;
  const int wc = wid >> 1, wn = wid & 1;
  const int lr = lane & 15, lq = lane >> 4;

  f32x4 acc[4][2];
  #pragma unroll
  for (int i = 0; i < 4; ++i)
    #pragma unroll
    for (int j = 0; j < 2; ++j) acc[i][j] = (f32x4){0.f,0.f,0.f,0.f};

  #pragma unroll 1
  for (int st = 0; st < 16; ++st){
    const int mc = ks * (NN / KSL) + st * 64;
    #pragma unroll
    for (int it = 0; it < 4; ++it){
      int seg = wid * 4 + it;
      int row = seg * 8 + (lane >> 3);
      int us  = (lane & 7) ^ (row & 7);
      __builtin_amdgcn_global_load_lds(GPTR(G + (size_t)row * NN + mc + us*8),
                                       LPTR(As + seg*512), 16, 0, 0);
    }
    #pragma unroll
    for (int i = 0; i < 4; ++i){
      int idx = tid + i * 256;
      int r = idx >> 4;
      int q = idx & 15;
      int mm = mc + q * 4;
      union { half_t h[4]; uint2 u2; } ev, eo;
      ev.u2 = *(const uint2*)(STb + (size_t)(n0 + r) * NN + mm);
      float4 cr = *(const float4*)(corb + mm);
      eo.h[0] = (half_t)((float)ev.h[0] * cr.x);
      eo.h[1] = (half_t)((float)ev.h[1] * cr.y);
      eo.h[2] = (half_t)((float)ev.h[2] * cr.z);
      eo.h[3] = (half_t)((float)ev.h[3] * cr.w);
      int c4 = (q * 4) ^ ((r & 7) * 8);
      *(uint2*)(Bs + r * 64 + c4) = eo.u2;
    }
    asm volatile("s_waitcnt vmcnt(0)" ::: "memory");
    __syncthreads();

    #pragma unroll
    for (int kk = 0; kk < 2; ++kk){
      f16x8 af[4], bf[2];
      #pragma unroll
      for (int f = 0; f < 4; ++f){
        int rA = wc*64 + f*16 + lr;
        af[f] = *(const f16x8*)(As + rA*64 + ((kk*32 + lq*8) ^ ((rA & 7)*8)));
      }
      #pragma unroll
      for (int f = 0; f < 2; ++f){
        int rB = wn*32 + f*16 + lr;
        bf[f] = *(const f16x8*)(Bs + rB*64 + ((kk*32 + lq*8) ^ ((rB & 7)*8)));
      }
      #pragma unroll
      for (int fc = 0; fc < 4; ++fc)
        #pragma unroll
        for (int fn = 0; fn < 2; ++fn)
          acc[fc][fn] = __builtin_amdgcn_mfma_f32_16x16x32_f16(af[fc], bf[fn], acc[fc][fn], 0,0,0);
    }
    __syncthreads();
  }
  #pragma unroll
  for (int fc = 0; fc < 4; ++fc)
    #pragma unroll
    for (int r = 0; r < 4; ++r){
      int c = wc*64 + fc*16 + lq*4 + r;
      float* dst = yp + (((size_t)b * KSL + ks) * CP + c) * NN + n0;
      #pragma unroll
      for (int fn = 0; fn < 2; ++fn) dst[wn*32 + fn*16 + lr] = acc[fc][fn][r];
    }
}

// ---------------- K5: z = Wz @ y (fp32; sums the KSL partials in staging) ---
__global__ __launch_bounds__(256) void z_gemm(
    const float* __restrict__ Wz, const float* __restrict__ yp,
    float* __restrict__ z)
{
  const int b  = blockIdx.z;
  const int o0 = blockIdx.y * 128;
  const int n0 = blockIdx.x * 64;
  const float* y0 = yp + ((size_t)b * KSL + 0) * CP * NN;
  const float* y1 = yp + ((size_t)b * KSL + 1) * CP * NN;
  const float* y2 = yp + ((size_t)b * KSL + 2) * CP * NN;
  const float* y3 = yp + ((size_t)b * KSL + 3) * CP * NN;
  float* zb = z + (size_t)b * CIN * NN;

  __shared__ float a_s[32][132];
  __shared__ float b_s[32][64];

  const int tid = threadIdx.x;
  const int tx = tid & 15, ty = tid >> 4;

  float acc[2][4][4];
  #pragma unroll
  for (int qa = 0; qa < 2; ++qa)
    #pragma unroll
    for (int i = 0; i < 4; ++i)
      #pragma unroll
      for (int j = 0; j < 4; ++j) acc[qa][i][j] = 0.f;

  for (int k0 = 0; k0 < CP; k0 += 32){
    #pragma unroll
    for (int i = 0; i < 4; ++i){
      int f4i = tid + i * 256;
      int c  = f4i >> 3;
      int k4 = f4i & 7;
      float4 w = *(const float4*)(Wz + (size_t)(o0 + c) * CP + k0 + k4 * 4);
      a_s[k4*4+0][c] = w.x;
      a_s[k4*4+1][c] = w.y;
      a_s[k4*4+2][c] = w.z;
      a_s[k4*4+3][c] = w.w;
    }
    #pragma unroll
    for (int i = 0; i < 2; ++i){
      int f4i = tid + i * 256;
      int kk = f4i >> 4;
      int n4 = f4i & 15;
      const size_t off = (size_t)(k0 + kk) * NN + n0 + n4 * 4;
      float4 v0 = *(const float4*)(y0 + off);
      float4 v1 = *(const float4*)(y1 + off);
      float4 v2 = *(const float4*)(y2 + off);
      float4 v3 = *(const float4*)(y3 + off);
      float4 sv;
      sv.x = v0.x + v1.x + v2.x + v3.x;
      sv.y = v0.y + v1.y + v2.y + v3.y;
      sv.z = v0.z + v1.z + v2.z + v3.z;
      sv.w = v0.w + v1.w + v2.w + v3.w;
      *(float4*)&b_s[kk][n4*4] = sv;
    }
    __syncthreads();
    #pragma unroll
    for (int kk = 0; kk < 32; ++kk){
      float af[8], bf[4];
      *(float4*)&af[0] = *(const float4*)&a_s[kk][ty*4];
      *(float4*)&af[4] = *(const float4*)&a_s[kk][ty*4+64];
      *(float4*)&bf[0] = *(const float4*)&b_s[kk][tx*4];
      #pragma unroll
      for (int qa = 0; qa < 2; ++qa)
        #pragma unroll
        for (int i = 0; i < 4; ++i)
          #pragma unroll
          for (int j = 0; j < 4; ++j)
            acc[qa][i][j] = fmaf(af[qa*4+i], bf[j], acc[qa][i][j]);
    }
    __syncthreads();
  }
  #pragma unroll
  for (int qa = 0; qa < 2; ++qa)
    #pragma unroll
    for (int i = 0; i < 4; ++i){
      const int row = o0 + qa*64 + ty*4 + i;
      float4 v = make_float4(acc[qa][i][0], acc[qa][i][1],
                             acc[qa][i][2], acc[qa][i][3]);
      *(float4*)(zb + (size_t)row * NN + n0 + tx*4) = v;
    }
}

// ---------------- K6: BatchNorm batch stats ---------------------------------
__global__ __launch_bounds__(256) void bn_stats(
    const float* __restrict__ z, float* __restrict__ mean,
    float* __restrict__ rstd)
{
  const int c = blockIdx.x;
  const int tid = threadIdx.x;
  float s = 0.f, s2 = 0.f;
  for (int b = 0; b < B_SZ; ++b){
    const float4* row = (const float4*)(z + ((size_t)b * CIN + c) * NN);
    #pragma unroll
    for (int i = 0; i < 4; ++i){
      float4 v = row[tid + i*256];
      s  += v.x + v.y + v.z + v.w;
      s2 += v.x*v.x + v.y*v.y + v.z*v.z + v.w*v.w;
    }
  }
  s  = wave_sum64(s);
  s2 = wave_sum64(s2);
  __shared__ float rs[4];
  __shared__ float rq[4];
  const int wid = tid >> 6, lane = tid & 63;
  if (lane == 0){ rs[wid] = s; rq[wid] = s2; }
  __syncthreads();
  if (tid == 0){
    const float S1 = rs[0]+rs[1]+rs[2]+rs[3];
    const float S2 = rq[0]+rq[1]+rq[2]+rq[3];
    const float inv = 1.f / (float)(B_SZ * NN);
    const float m = S1 * inv;
    const float var = S2 * inv - m * m;
    mean[c] = m;
    rstd[c] = 1.f / sqrtf(var + 1e-5f);
  }
}

// ---------------- K7: out = (z-mean)*rstd*gamma + beta + x ------------------
__global__ __launch_bounds__(256) void finalize_k(
    const float* __restrict__ z, const float* __restrict__ x,
    const float* __restrict__ mean, const float* __restrict__ rstd,
    const float* __restrict__ gamma, const float* __restrict__ beta,
    float* __restrict__ out)
{
  const int total = B_SZ * CIN * NN / 4;
  for (int i = blockIdx.x * blockDim.x + threadIdx.x; i < total;
       i += gridDim.x * blockDim.x){
    const int c = (i >> 10) & (CIN - 1);
    float4 zv = ((const float4*)z)[i];
    float4 xv = ((const float4*)x)[i];
    const float m = mean[c], r = rstd[c], ga = gamma[c], be = beta[c];
    float4 o;
    o.x = (zv.x - m) * r * ga + be + xv.x;
    o.y = (zv.y - m) * r * ga + be + xv.y;
    o.z = (zv.z - m) * r * ga + be + xv.z;
    o.w = (zv.w - m) * r * ga + be + xv.w;
    ((float4*)out)[i] = o;
  }
}

// ---------------- launcher --------------------------------------------------
extern "C" void kernel_launch(void* const* d_in, const int* in_sizes, int n_in,
                              void* d_out, int out_size, void* d_ws, size_t ws_size,
                              hipStream_t stream)
{
  const float* x     = (const float*)d_in[0];
  const float* Wt    = (const float*)d_in[1];
  const float* Wp    = (const float*)d_in[2];
  const float* Wg    = (const float*)d_in[3];
  const float* Wz    = (const float*)d_in[4];
  const float* gamma = (const float*)d_in[5];
  const float* beta  = (const float*)d_in[6];
  float* out = (float*)d_out;

  float* wsf = (float*)d_ws;
  size_t off = 0;
  half_t* ST  = (half_t*)(wsf + off); off += (size_t)B_SZ * NN * NN / 2;   // 134MB
  half_t* tTh = (half_t*)(wsf + off); off += (size_t)B_SZ*NN*CP/2;
  half_t* tTl = (half_t*)(wsf + off); off += (size_t)B_SZ*NN*CP/2;
  half_t* pTh = (half_t*)(wsf + off); off += (size_t)B_SZ*NN*CP/2;
  half_t* pTl = (half_t*)(wsf + off); off += (size_t)B_SZ*NN*CP/2;
  half_t* gF  = (half_t*)(wsf + off); off += (size_t)B_SZ*CP*NN/2;
  half_t* xTh = (half_t*)(wsf + off); off += (size_t)B_SZ*NN*CIN/2;
  half_t* xTl = (half_t*)(wsf + off); off += (size_t)B_SZ*NN*CIN/2;
  half_t* Wh  = (half_t*)(wsf + off); off += (size_t)3*CP*CIN/2;
  half_t* Wl  = (half_t*)(wsf + off); off += (size_t)3*CP*CIN/2;
  float*  yp  = wsf + off; off += (size_t)B_SZ * KSL * CP * NN;            // 33.5MB
  float*  pmax= wsf + off; off += (size_t)B_SZ * NT * NN;
  float*  psum= wsf + off; off += (size_t)B_SZ * NT * NN;
  float*  corr= wsf + off; off += (size_t)B_SZ * NT * NN;
  float*  meanb = wsf + off; off += CIN;
  float*  rstdb = wsf + off; off += CIN;
  float*  z = (float*)ST;   // alias: ST dead after y_gemm

  split_w <<<dim3(3, 4),           256, 0, stream>>>(Wt, Wp, Wg, Wh, Wl);
  split_x <<<dim3(64, 4, B_SZ),    256, 0, stream>>>(x, xTh, xTl);
  tpg_gemm<<<dim3(64, 3, B_SZ),    256, 0, stream>>>(Wh, Wl, xTh, xTl,
                                                     tTh, tTl, pTh, pTl, gF);
  s_gemm    <<<dim3(32, 32, B_SZ), 256, 0, stream>>>(tTh, tTl, pTh,
                                                     ST, pmax, psum);
  merge_corr<<<dim3(16, B_SZ),     256, 0, stream>>>(pmax, psum, corr);
  y_gemm    <<<dim3(64, KSL, B_SZ),256, 0, stream>>>(gF, ST, corr, yp);
  z_gemm    <<<dim3(64, 2, B_SZ),  256, 0, stream>>>(Wz, yp, z);
  bn_stats  <<<dim3(CIN),          256, 0, stream>>>(z, meanb, rstdb);
  finalize_k<<<dim3(2048),         256, 0, stream>>>(z, x, meanb, rstdb,
                                                     gamma, beta, out);
}

// Round 9
// 220.808 us; speedup vs baseline: 1.2450x; 1.0417x over previous
//
#include <hip/hip_runtime.h>
#include <hip/hip_fp16.h>

#define B_SZ 4
#define CIN  256
#define CP   128
#define NN   4096
#define NT   32          // 128-row n-tiles per batch (softmax partials)
#define KSL  4           // k-slices in y_gemm (K=1024 each)

typedef _Float16 half_t;
typedef _Float16 f16x8 __attribute__((ext_vector_type(8)));
typedef float f32x4 __attribute__((ext_vector_type(4)));

#define GPTR(p) ((const __attribute__((address_space(1))) void*)(p))
#define LPTR(p) ((__attribute__((address_space(3))) void*)(p))

__device__ __forceinline__ float wave_sum64(float v){
  #pragma unroll
  for (int o = 32; o > 0; o >>= 1) v += __shfl_xor(v, o, 64);
  return v;
}

// ---------------- K0a: split W*16 into fp16 hi/lo ---------------------------
__global__ __launch_bounds__(256) void split_w(
    const float* __restrict__ Wt, const float* __restrict__ Wp,
    const float* __restrict__ Wg, half_t* __restrict__ Wh,
    half_t* __restrict__ Wl)
{
  const int sel = blockIdx.x;
  const float* W = (sel == 0) ? Wt : ((sel == 1) ? Wp : Wg);
  half_t* oh = Wh + sel * (CP * CIN);
  half_t* ol = Wl + sel * (CP * CIN);
  #pragma unroll
  for (int i = 0; i < 8; ++i){
    int i4 = blockIdx.y * 2048 + threadIdx.x + i * 256;
    float4 v = ((const float4*)W)[i4];
    v.x *= 16.f; v.y *= 16.f; v.z *= 16.f; v.w *= 16.f;
    union { half_t h[4]; uint2 u; } hh, ll;
    hh.h[0] = (half_t)v.x; ll.h[0] = (half_t)(v.x - (float)hh.h[0]);
    hh.h[1] = (half_t)v.y; ll.h[1] = (half_t)(v.y - (float)hh.h[1]);
    hh.h[2] = (half_t)v.z; ll.h[2] = (half_t)(v.z - (float)hh.h[2]);
    hh.h[3] = (half_t)v.w; ll.h[3] = (half_t)(v.w - (float)hh.h[3]);
    *(uint2*)(oh + i4 * 4) = hh.u;
    *(uint2*)(ol + i4 * 4) = ll.u;
  }
}

// ---------------- K0b: transpose-split x -> xT hi/lo [b][n][c] --------------
__global__ __launch_bounds__(256) void split_x(
    const float* __restrict__ x, half_t* __restrict__ xTh,
    half_t* __restrict__ xTl)
{
  const int b  = blockIdx.z;
  const int c0 = blockIdx.y * 64;
  const int n0 = blockIdx.x * 64;
  __shared__ float lds[64][68];
  const int tid = threadIdx.x;
  #pragma unroll
  for (int i = 0; i < 4; ++i){
    int idx = tid + i * 256;
    int cr = idx >> 4, nq = idx & 15;
    float4 v = *(const float4*)(x + ((size_t)b * CIN + c0 + cr) * NN + n0 + nq * 4);
    *(float4*)&lds[cr][nq * 4] = v;
  }
  __syncthreads();
  #pragma unroll
  for (int i = 0; i < 8; ++i){
    int idx = tid + i * 256;
    int nl = idx >> 5;
    int cp = (idx & 31) * 2;
    float v0 = lds[cp][nl], v1 = lds[cp + 1][nl];
    half_t h0 = (half_t)v0, h1 = (half_t)v1;
    half_t l0 = (half_t)(v0 - (float)h0), l1 = (half_t)(v1 - (float)h1);
    union { half_t h[2]; unsigned int u; } ph, pl;
    ph.h[0] = h0; ph.h[1] = h1;
    pl.h[0] = l0; pl.h[1] = l1;
    size_t o = ((size_t)b * NN + n0 + nl) * CIN + c0 + cp;
    *(unsigned int*)(xTh + o) = ph.u;
    *(unsigned int*)(xTl + o) = pl.u;
  }
}

// ---------------- K1: t/p/g via fp16 3-slab MFMA ----------------------------
// Internal 3-slab accuracy (t must be accurate BEFORE fp16 rounding); outputs
// hi-only fp16: tT/pT [b][n][CP], gF [b][CP][NN].
__global__ __launch_bounds__(256) void tpg_gemm(
    const half_t* __restrict__ Wh, const half_t* __restrict__ Wl,
    const half_t* __restrict__ xTh, const half_t* __restrict__ xTl,
    half_t* __restrict__ tT, half_t* __restrict__ pT,
    half_t* __restrict__ gF)
{
  const int b   = blockIdx.z;
  const int sel = blockIdx.y;
  const int n0  = blockIdx.x * 64;
  const half_t* Ah_g = Wh + sel * (CP * CIN);
  const half_t* Al_g = Wl + sel * (CP * CIN);
  const half_t* Bh_g = xTh + ((size_t)b * NN + n0) * CIN;
  const half_t* Bl_g = xTl + ((size_t)b * NN + n0) * CIN;

  __shared__ half_t lds[24576];   // Ah 0 | Al 8192 | Bh 16384 | Bl 20480
  const int tid = threadIdx.x;
  const int wid = tid >> 6, lane = tid & 63;
  const int wo = wid >> 1, wn = wid & 1;
  const int lr = lane & 15, lq = lane >> 4;

  f32x4 acc[4][2];
  #pragma unroll
  for (int i = 0; i < 4; ++i)
    #pragma unroll
    for (int j = 0; j < 2; ++j) acc[i][j] = (f32x4){0.f,0.f,0.f,0.f};

  #pragma unroll 1
  for (int kc = 0; kc < CIN; kc += 64){
    #pragma unroll
    for (int it = 0; it < 4; ++it){
      int seg = wid * 4 + it;
      int row = seg * 8 + (lane >> 3);
      int us  = (lane & 7) ^ (row & 7);
      size_t go = (size_t)row * CIN + kc + us * 8;
      __builtin_amdgcn_global_load_lds(GPTR(Ah_g + go), LPTR(lds + seg*512), 16, 0, 0);
      __builtin_amdgcn_global_load_lds(GPTR(Al_g + go), LPTR(lds + 8192 + seg*512), 16, 0, 0);
    }
    #pragma unroll
    for (int it = 0; it < 2; ++it){
      int seg = wid * 2 + it;
      int row = seg * 8 + (lane >> 3);
      int us  = (lane & 7) ^ (row & 7);
      size_t go = (size_t)row * CIN + kc + us * 8;
      __builtin_amdgcn_global_load_lds(GPTR(Bh_g + go), LPTR(lds + 16384 + seg*512), 16, 0, 0);
      __builtin_amdgcn_global_load_lds(GPTR(Bl_g + go), LPTR(lds + 20480 + seg*512), 16, 0, 0);
    }
    asm volatile("s_waitcnt vmcnt(0)" ::: "memory");
    __syncthreads();

    #pragma unroll
    for (int kk = 0; kk < 2; ++kk){
      f16x8 ah[4], al4[4], bh[2], bl[2];
      #pragma unroll
      for (int f = 0; f < 4; ++f){
        int rA = wo * 64 + f * 16 + lr;
        int cA = (kk*32 + lq*8) ^ ((rA & 7) * 8);
        ah[f]  = *(const f16x8*)(lds + rA * 64 + cA);
        al4[f] = *(const f16x8*)(lds + 8192 + rA * 64 + cA);
      }
      #pragma unroll
      for (int f = 0; f < 2; ++f){
        int rB = wn * 32 + f * 16 + lr;
        int cB = (kk*32 + lq*8) ^ ((rB & 7) * 8);
        bh[f] = *(const f16x8*)(lds + 16384 + rB * 64 + cB);
        bl[f] = *(const f16x8*)(lds + 20480 + rB * 64 + cB);
      }
      #pragma unroll
      for (int fo = 0; fo < 4; ++fo)
        #pragma unroll
        for (int fn = 0; fn < 2; ++fn){
          acc[fo][fn] = __builtin_amdgcn_mfma_f32_16x16x32_f16(ah[fo],  bh[fn], acc[fo][fn], 0,0,0);
          acc[fo][fn] = __builtin_amdgcn_mfma_f32_16x16x32_f16(al4[fo], bh[fn], acc[fo][fn], 0,0,0);
          acc[fo][fn] = __builtin_amdgcn_mfma_f32_16x16x32_f16(ah[fo],  bl[fn], acc[fo][fn], 0,0,0);
        }
    }
    __syncthreads();
  }

  if (sel < 2){
    half_t* Ohi = ((sel == 0) ? tT : pT) + (size_t)b * NN * CP;
    float (*ldsT)[132] = (float (*)[132])lds;
    #pragma unroll
    for (int fo = 0; fo < 4; ++fo)
      #pragma unroll
      for (int fn = 0; fn < 2; ++fn)
        #pragma unroll
        for (int r = 0; r < 4; ++r){
          int n = wn * 32 + fn * 16 + lr;
          int o = wo * 64 + fo * 16 + lq * 4 + r;
          ldsT[n][o] = acc[fo][fn][r] * 0.0625f;
        }
    __syncthreads();
    #pragma unroll
    for (int it = 0; it < 16; ++it){
      int idx = tid + it * 256;
      int nl = idx >> 6;
      int cp = (idx & 63) * 2;
      float v0 = ldsT[nl][cp], v1 = ldsT[nl][cp + 1];
      union { half_t h[2]; unsigned int u; } ph;
      ph.h[0] = (half_t)v0; ph.h[1] = (half_t)v1;
      *(unsigned int*)(Ohi + (size_t)(n0 + nl) * CP + cp) = ph.u;
    }
  } else {
    half_t* G = gF + (size_t)b * CP * NN;
    #pragma unroll
    for (int fo = 0; fo < 4; ++fo)
      #pragma unroll
      for (int r = 0; r < 4; ++r){
        int o = wo * 64 + fo * 16 + lq * 4 + r;
        #pragma unroll
        for (int fn = 0; fn < 2; ++fn){
          int n = n0 + wn * 32 + fn * 16 + lr;
          G[(size_t)o * NN + n] = (half_t)(acc[fo][fn][r] * 0.0625f);
        }
      }
  }
}

// ---------------- K2: S^T tile + fused col-stats + E(fp16) store ------------
// 1-slab: S = t*p in fp16 inputs / fp32 acc (error below the E-fp16 floor).
__global__ __launch_bounds__(256) void s_gemm(
    const half_t* __restrict__ tT, const half_t* __restrict__ pT,
    half_t* __restrict__ ST, float* __restrict__ pmax,
    float* __restrict__ psum)
{
  const int b  = blockIdx.z;
  const int m0 = blockIdx.x * 128;
  const int n0 = blockIdx.y * 128;
  const size_t tb = (size_t)b * NN * CP;
  half_t* STb = ST + (size_t)b * NN * NN;
  __shared__ half_t lds[2 * 128 * 64];       // A | B, 32 KB
  const int tid = threadIdx.x;
  const int wid = tid >> 6, lane = tid & 63;
  const int wn = wid >> 1, wm = wid & 1;
  const int lr = lane & 15, lq = lane >> 4;

  f32x4 acc[4][4];
  #pragma unroll
  for (int i = 0; i < 4; ++i)
    #pragma unroll
    for (int j = 0; j < 4; ++j) acc[i][j] = (f32x4){0.f,0.f,0.f,0.f};

  const half_t* baseA = tT + tb + (size_t)n0 * CP;
  const half_t* baseB = pT + tb + (size_t)m0 * CP;

  #pragma unroll 1
  for (int kc = 0; kc < CP; kc += 64){
    #pragma unroll
    for (int it = 0; it < 4; ++it){
      int seg = wid * 4 + it;
      int row = seg * 8 + (lane >> 3);
      int us  = (lane & 7) ^ (row & 7);
      size_t go = (size_t)row * CP + kc + us * 8;
      __builtin_amdgcn_global_load_lds(GPTR(baseA + go), LPTR(lds + seg*512), 16, 0, 0);
      __builtin_amdgcn_global_load_lds(GPTR(baseB + go), LPTR(lds + 8192 + seg*512), 16, 0, 0);
    }
    asm volatile("s_waitcnt vmcnt(0)" ::: "memory");
    __syncthreads();

    #pragma unroll
    for (int kk = 0; kk < 2; ++kk){
      f16x8 ah[4], bh[4];
      #pragma unroll
      for (int f = 0; f < 4; ++f){
        int rA = wn*64 + f*16 + lr;
        ah[f] = *(const f16x8*)(lds + rA*64 + ((kk*32 + lq*8) ^ ((rA & 7) * 8)));
        int rB = wm*64 + f*16 + lr;
        bh[f] = *(const f16x8*)(lds + 8192 + rB*64 + ((kk*32 + lq*8) ^ ((rB & 7) * 8)));
      }
      #pragma unroll
      for (int fn = 0; fn < 4; ++fn)
        #pragma unroll
        for (int fm = 0; fm < 4; ++fm)
          acc[fn][fm] = __builtin_amdgcn_mfma_f32_16x16x32_f16(ah[fn], bh[fm], acc[fn][fm], 0,0,0);
    }
    __syncthreads();
  }

  // ---- fused column-stats epilogue ----
  float* red  = (float*)lds;
  float* red2 = (float*)lds + 256;

  float cmax[4];
  #pragma unroll
  for (int fm = 0; fm < 4; ++fm){
    float t = -3.0e38f;
    #pragma unroll
    for (int fn = 0; fn < 4; ++fn)
      #pragma unroll
      for (int r = 0; r < 4; ++r) t = fmaxf(t, acc[fn][fm][r]);
    t = fmaxf(t, __shfl_xor(t, 16, 64));
    t = fmaxf(t, __shfl_xor(t, 32, 64));
    cmax[fm] = t;
  }
  if (lq == 0){
    #pragma unroll
    for (int fm = 0; fm < 4; ++fm) red[(wid*4+fm)*16 + lr] = cmax[fm];
  }
  __syncthreads();
  #pragma unroll
  for (int fm = 0; fm < 4; ++fm)
    cmax[fm] = fmaxf(red[((wm)*4+fm)*16 + lr], red[((2+wm)*4+fm)*16 + lr]);

  float csum[4] = {0.f, 0.f, 0.f, 0.f};
  #pragma unroll
  for (int fn = 0; fn < 4; ++fn)
    #pragma unroll
    for (int r = 0; r < 4; ++r){
      int n = n0 + wn*64 + fn*16 + lq*4 + r;
      half_t* dst = STb + (size_t)n * NN + m0 + wm*64;
      #pragma unroll
      for (int fm = 0; fm < 4; ++fm){
        float e = __expf(acc[fn][fm][r] - cmax[fm]);
        csum[fm] += e;
        dst[fm*16 + lr] = (half_t)e;
      }
    }
  #pragma unroll
  for (int fm = 0; fm < 4; ++fm){
    csum[fm] += __shfl_xor(csum[fm], 16, 64);
    csum[fm] += __shfl_xor(csum[fm], 32, 64);
  }
  __syncthreads();
  if (lq == 0){
    #pragma unroll
    for (int fm = 0; fm < 4; ++fm) red2[(wid*4+fm)*16 + lr] = csum[fm];
  }
  __syncthreads();
  if (wn == 0 && lq == 0){
    #pragma unroll
    for (int fm = 0; fm < 4; ++fm){
      int m = m0 + wm*64 + fm*16 + lr;
      pmax[((size_t)b * NT + blockIdx.y) * NN + m] = cmax[fm];
      psum[((size_t)b * NT + blockIdx.y) * NN + m] = red2[((wm)*4+fm)*16 + lr]
                                                   + red2[((2+wm)*4+fm)*16 + lr];
    }
  }
}

// ---------------- K3: merge tile partials -> corr[b][nt][m] -----------------
__global__ __launch_bounds__(256) void merge_corr(
    const float* __restrict__ pmax, const float* __restrict__ psum,
    float* __restrict__ corr)
{
  const size_t base = (size_t)blockIdx.y * NT * NN;
  const int m = blockIdx.x * 256 + threadIdx.x;
  float pm[NT];
  float mx = -3.0e38f;
  #pragma unroll
  for (int nt = 0; nt < NT; ++nt){
    pm[nt] = pmax[base + (size_t)nt * NN + m];
    mx = fmaxf(mx, pm[nt]);
  }
  float den = 0.f;
  #pragma unroll
  for (int nt = 0; nt < NT; ++nt){
    pm[nt] = __expf(pm[nt] - mx);
    den += psum[base + (size_t)nt * NN + m] * pm[nt];
  }
  const float r = 1.f / den;
  #pragma unroll
  for (int nt = 0; nt < NT; ++nt)
    corr[base + (size_t)nt * NN + m] = pm[nt] * r;
}

// ---------------- K4: yp[b][ks][c][n] = sum_m g[c][m]*(E[n][m]*corr) --------
// 128c x 128n tile, K = 1024 per slice.
__global__ __launch_bounds__(256) void y_gemm(
    const half_t* __restrict__ gF, const half_t* __restrict__ ST,
    const float* __restrict__ corr, float* __restrict__ yp)
{
  const int b  = blockIdx.z;
  const int nt = blockIdx.x;              // 128-row n-tile == corr tile
  const int n0 = nt * 128;
  const int ks = blockIdx.y;
  const half_t* G   = gF + (size_t)b * CP * NN;
  const half_t* STb = ST + (size_t)b * NN * NN;
  const float* corb = corr + ((size_t)b * NT + nt) * NN;
  __shared__ half_t As[128*64];           // g[c][m-chunk] 16KB
  __shared__ half_t Bs[128*64];           // E'[n][m-chunk] 16KB
  const int tid = threadIdx.x;
  const int wid = tid >> 6, lane = tid & 63;
  const int wc = wid >> 1, wn = wid & 1;
  const int lr = lane & 15, lq = lane >> 4;

  f32x4 acc[4][4];
  #pragma unroll
  for (int i = 0; i < 4; ++i)
    #pragma unroll
    for (int j = 0; j < 4; ++j) acc[i][j] = (f32x4){0.f,0.f,0.f,0.f};

  #pragma unroll 1
  for (int st = 0; st < 16; ++st){
    const int mc = ks * (NN / KSL) + st * 64;
    #pragma unroll
    for (int it = 0; it < 4; ++it){
      int seg = wid * 4 + it;
      int row = seg * 8 + (lane >> 3);
      int us  = (lane & 7) ^ (row & 7);
      __builtin_amdgcn_global_load_lds(GPTR(G + (size_t)row * NN + mc + us*8),
                                       LPTR(As + seg*512), 16, 0, 0);
    }
    #pragma unroll
    for (int i = 0; i < 8; ++i){
      int idx = tid + i * 256;             // 2048 uint2 units
      int r = idx >> 4;                    // n row 0..127
      int q = idx & 15;                    // m quad
      int mm = mc + q * 4;
      union { half_t h[4]; uint2 u2; } ev, eo;
      ev.u2 = *(const uint2*)(STb + (size_t)(n0 + r) * NN + mm);
      float4 cr = *(const float4*)(corb + mm);
      eo.h[0] = (half_t)((float)ev.h[0] * cr.x);
      eo.h[1] = (half_t)((float)ev.h[1] * cr.y);
      eo.h[2] = (half_t)((float)ev.h[2] * cr.z);
      eo.h[3] = (half_t)((float)ev.h[3] * cr.w);
      int c4 = (q * 4) ^ ((r & 7) * 8);
      *(uint2*)(Bs + r * 64 + c4) = eo.u2;
    }
    asm volatile("s_waitcnt vmcnt(0)" ::: "memory");
    __syncthreads();

    #pragma unroll
    for (int kk = 0; kk < 2; ++kk){
      f16x8 af[4], bf[4];
      #pragma unroll
      for (int f = 0; f < 4; ++f){
        int rA = wc*64 + f*16 + lr;
        af[f] = *(const f16x8*)(As + rA*64 + ((kk*32 + lq*8) ^ ((rA & 7)*8)));
        int rB = wn*64 + f*16 + lr;
        bf[f] = *(const f16x8*)(Bs + rB*64 + ((kk*32 + lq*8) ^ ((rB & 7)*8)));
      }
      #pragma unroll
      for (int fc = 0; fc < 4; ++fc)
        #pragma unroll
        for (int fn = 0; fn < 4; ++fn)
          acc[fc][fn] = __builtin_amdgcn_mfma_f32_16x16x32_f16(af[fc], bf[fn], acc[fc][fn], 0,0,0);
    }
    __syncthreads();
  }
  #pragma unroll
  for (int fc = 0; fc < 4; ++fc)
    #pragma unroll
    for (int r = 0; r < 4; ++r){
      int c = wc*64 + fc*16 + lq*4 + r;
      float* dst = yp + (((size_t)b * KSL + ks) * CP + c) * NN + n0;
      #pragma unroll
      for (int fn = 0; fn < 4; ++fn) dst[wn*64 + fn*16 + lr] = acc[fc][fn][r];
    }
}

// ---------------- K5: z = Wz @ y (fp32; sums the KSL partials in staging) ---
__global__ __launch_bounds__(256) void z_gemm(
    const float* __restrict__ Wz, const float* __restrict__ yp,
    float* __restrict__ z)
{
  const int b  = blockIdx.z;
  const int o0 = blockIdx.y * 128;
  const int n0 = blockIdx.x * 64;
  const float* y0 = yp + ((size_t)b * KSL + 0) * CP * NN;
  const float* y1 = yp + ((size_t)b * KSL + 1) * CP * NN;
  const float* y2 = yp + ((size_t)b * KSL + 2) * CP * NN;
  const float* y3 = yp + ((size_t)b * KSL + 3) * CP * NN;
  float* zb = z + (size_t)b * CIN * NN;

  __shared__ float a_s[32][132];
  __shared__ float b_s[32][64];

  const int tid = threadIdx.x;
  const int tx = tid & 15, ty = tid >> 4;

  float acc[2][4][4];
  #pragma unroll
  for (int qa = 0; qa < 2; ++qa)
    #pragma unroll
    for (int i = 0; i < 4; ++i)
      #pragma unroll
      for (int j = 0; j < 4; ++j) acc[qa][i][j] = 0.f;

  for (int k0 = 0; k0 < CP; k0 += 32){
    #pragma unroll
    for (int i = 0; i < 4; ++i){
      int f4i = tid + i * 256;
      int c  = f4i >> 3;
      int k4 = f4i & 7;
      float4 w = *(const float4*)(Wz + (size_t)(o0 + c) * CP + k0 + k4 * 4);
      a_s[k4*4+0][c] = w.x;
      a_s[k4*4+1][c] = w.y;
      a_s[k4*4+2][c] = w.z;
      a_s[k4*4+3][c] = w.w;
    }
    #pragma unroll
    for (int i = 0; i < 2; ++i){
      int f4i = tid + i * 256;
      int kk = f4i >> 4;
      int n4 = f4i & 15;
      const size_t off = (size_t)(k0 + kk) * NN + n0 + n4 * 4;
      float4 v0 = *(const float4*)(y0 + off);
      float4 v1 = *(const float4*)(y1 + off);
      float4 v2 = *(const float4*)(y2 + off);
      float4 v3 = *(const float4*)(y3 + off);
      float4 sv;
      sv.x = v0.x + v1.x + v2.x + v3.x;
      sv.y = v0.y + v1.y + v2.y + v3.y;
      sv.z = v0.z + v1.z + v2.z + v3.z;
      sv.w = v0.w + v1.w + v2.w + v3.w;
      *(float4*)&b_s[kk][n4*4] = sv;
    }
    __syncthreads();
    #pragma unroll
    for (int kk = 0; kk < 32; ++kk){
      float af[8], bf[4];
      *(float4*)&af[0] = *(const float4*)&a_s[kk][ty*4];
      *(float4*)&af[4] = *(const float4*)&a_s[kk][ty*4+64];
      *(float4*)&bf[0] = *(const float4*)&b_s[kk][tx*4];
      #pragma unroll
      for (int qa = 0; qa < 2; ++qa)
        #pragma unroll
        for (int i = 0; i < 4; ++i)
          #pragma unroll
          for (int j = 0; j < 4; ++j)
            acc[qa][i][j] = fmaf(af[qa*4+i], bf[j], acc[qa][i][j]);
    }
    __syncthreads();
  }
  #pragma unroll
  for (int qa = 0; qa < 2; ++qa)
    #pragma unroll
    for (int i = 0; i < 4; ++i){
      const int row = o0 + qa*64 + ty*4 + i;
      float4 v = make_float4(acc[qa][i][0], acc[qa][i][1],
                             acc[qa][i][2], acc[qa][i][3]);
      *(float4*)(zb + (size_t)row * NN + n0 + tx*4) = v;
    }
}

// ---------------- K6: BatchNorm batch stats ---------------------------------
__global__ __launch_bounds__(256) void bn_stats(
    const float* __restrict__ z, float* __restrict__ mean,
    float* __restrict__ rstd)
{
  const int c = blockIdx.x;
  const int tid = threadIdx.x;
  float s = 0.f, s2 = 0.f;
  for (int b = 0; b < B_SZ; ++b){
    const float4* row = (const float4*)(z + ((size_t)b * CIN + c) * NN);
    #pragma unroll
    for (int i = 0; i < 4; ++i){
      float4 v = row[tid + i*256];
      s  += v.x + v.y + v.z + v.w;
      s2 += v.x*v.x + v.y*v.y + v.z*v.z + v.w*v.w;
    }
  }
  s  = wave_sum64(s);
  s2 = wave_sum64(s2);
  __shared__ float rs[4];
  __shared__ float rq[4];
  const int wid = tid >> 6, lane = tid & 63;
  if (lane == 0){ rs[wid] = s; rq[wid] = s2; }
  __syncthreads();
  if (tid == 0){
    const float S1 = rs[0]+rs[1]+rs[2]+rs[3];
    const float S2 = rq[0]+rq[1]+rq[2]+rq[3];
    const float inv = 1.f / (float)(B_SZ * NN);
    const float m = S1 * inv;
    const float var = S2 * inv - m * m;
    mean[c] = m;
    rstd[c] = 1.f / sqrtf(var + 1e-5f);
  }
}

// ---------------- K7: out = (z-mean)*rstd*gamma + beta + x ------------------
__global__ __launch_bounds__(256) void finalize_k(
    const float* __restrict__ z, const float* __restrict__ x,
    const float* __restrict__ mean, const float* __restrict__ rstd,
    const float* __restrict__ gamma, const float* __restrict__ beta,
    float* __restrict__ out)
{
  const int total = B_SZ * CIN * NN / 4;
  for (int i = blockIdx.x * blockDim.x + threadIdx.x; i < total;
       i += gridDim.x * blockDim.x){
    const int c = (i >> 10) & (CIN - 1);
    float4 zv = ((const float4*)z)[i];
    float4 xv = ((const float4*)x)[i];
    const float m = mean[c], r = rstd[c], ga = gamma[c], be = beta[c];
    float4 o;
    o.x = (zv.x - m) * r * ga + be + xv.x;
    o.y = (zv.y - m) * r * ga + be + xv.y;
    o.z = (zv.z - m) * r * ga + be + xv.z;
    o.w = (zv.w - m) * r * ga + be + xv.w;
    ((float4*)out)[i] = o;
  }
}

// ---------------- launcher --------------------------------------------------
extern "C" void kernel_launch(void* const* d_in, const int* in_sizes, int n_in,
                              void* d_out, int out_size, void* d_ws, size_t ws_size,
                              hipStream_t stream)
{
  const float* x     = (const float*)d_in[0];
  const float* Wt    = (const float*)d_in[1];
  const float* Wp    = (const float*)d_in[2];
  const float* Wg    = (const float*)d_in[3];
  const float* Wz    = (const float*)d_in[4];
  const float* gamma = (const float*)d_in[5];
  const float* beta  = (const float*)d_in[6];
  float* out = (float*)d_out;

  float* wsf = (float*)d_ws;
  size_t off = 0;
  half_t* ST  = (half_t*)(wsf + off); off += (size_t)B_SZ * NN * NN / 2;   // 134MB
  half_t* tT  = (half_t*)(wsf + off); off += (size_t)B_SZ*NN*CP/2;
  half_t* pT  = (half_t*)(wsf + off); off += (size_t)B_SZ*NN*CP/2;
  half_t* gF  = (half_t*)(wsf + off); off += (size_t)B_SZ*CP*NN/2;
  half_t* xTh = (half_t*)(wsf + off); off += (size_t)B_SZ*NN*CIN/2;
  half_t* xTl = (half_t*)(wsf + off); off += (size_t)B_SZ*NN*CIN/2;
  half_t* Wh  = (half_t*)(wsf + off); off += (size_t)3*CP*CIN/2;
  half_t* Wl  = (half_t*)(wsf + off); off += (size_t)3*CP*CIN/2;
  float*  yp  = wsf + off; off += (size_t)B_SZ * KSL * CP * NN;            // 33.5MB
  float*  pmax= wsf + off; off += (size_t)B_SZ * NT * NN;
  float*  psum= wsf + off; off += (size_t)B_SZ * NT * NN;
  float*  corr= wsf + off; off += (size_t)B_SZ * NT * NN;
  float*  meanb = wsf + off; off += CIN;
  float*  rstdb = wsf + off; off += CIN;
  float*  z = (float*)ST;   // alias: ST dead after y_gemm

  split_w <<<dim3(3, 4),           256, 0, stream>>>(Wt, Wp, Wg, Wh, Wl);
  split_x <<<dim3(64, 4, B_SZ),    256, 0, stream>>>(x, xTh, xTl);
  tpg_gemm<<<dim3(64, 3, B_SZ),    256, 0, stream>>>(Wh, Wl, xTh, xTl,
                                                     tT, pT, gF);
  s_gemm    <<<dim3(32, 32, B_SZ), 256, 0, stream>>>(tT, pT, ST, pmax, psum);
  merge_corr<<<dim3(16, B_SZ),     256, 0, stream>>>(pmax, psum, corr);
  y_gemm    <<<dim3(32, KSL, B_SZ),256, 0, stream>>>(gF, ST, corr, yp);
  z_gemm    <<<dim3(64, 2, B_SZ),  256, 0, stream>>>(Wz, yp, z);
  bn_stats  <<<dim3(CIN),          256, 0, stream>>>(z, meanb, rstdb);
  finalize_k<<<dim3(2048),         256, 0, stream>>>(z, x, meanb, rstdb,
                                                     gamma, beta, out);
}